// Round 1
// baseline (168.008 us; speedup 1.0000x reference)
//
#include <hip/hip_runtime.h>
#include <hip/hip_bf16.h>

// Problem constants
#define B_    64
#define S_    512
#define W_    256
#define D_    768
#define NATTR 32
#define NN    96   // NATTR * 3

typedef __attribute__((ext_vector_type(8))) short bfrag;   // 8 bf16 in 4 VGPRs
typedef __attribute__((ext_vector_type(4))) float f32x4;

static __device__ __forceinline__ short f2bf(float f) {
  __hip_bfloat16 h = __float2bfloat16(f);   // RNE; compiler emits v_cvt_pk_bf16_f32 pairs
  return __builtin_bit_cast(short, h);
}

static __device__ __forceinline__ bfrag cvt8(f32x4 lo, f32x4 hi) {
  bfrag r;
  r[0] = f2bf(lo[0]); r[1] = f2bf(lo[1]); r[2] = f2bf(lo[2]); r[3] = f2bf(lo[3]);
  r[4] = f2bf(hi[0]); r[5] = f2bf(hi[1]); r[6] = f2bf(hi[2]); r[7] = f2bf(hi[3]);
  return r;
}

// Block: 32 pooled rows (one b, w0..w0+31) x all 96 output cols.
// 4 waves: wave wv -> msub = wv&1 (16-row half), nh = wv>>1 (48-col half).
// Each wave: 3x (16x16) accum tiles, K-loop 768 in steps of 32 (24 MFMAs per tile).
__global__ __launch_bounds__(256, 2) void ner_mfma_kernel(
    const float* __restrict__ seq, const int* __restrict__ widx,
    const float* __restrict__ cw, const float* __restrict__ cb,
    float* __restrict__ out)
{
  __shared__ float lds[32][NN + 1];   // +1 pad: 96 % 32 == 0 would alias banks

  const int tid  = threadIdx.x;
  const int lane = tid & 63;
  const int wv   = tid >> 6;
  const int r16  = lane & 15;   // row index of A-frag / col index of B-frag
  const int g    = lane >> 4;   // k-group 0..3 (8 consecutive k each)

  const int blk = blockIdx.x;
  const int b   = blk >> 3;            // 8 blocks per batch element
  const int w0  = (blk & 7) << 5;      // 32 w-rows per block

  const int msub = wv & 1;
  const int nh   = wv >> 1;            // col base 0 or 48

  // A (gathered pooled row) pointer for this lane
  const int wl   = w0 + msub * 16 + r16;
  const int sidx = widx[b * W_ + wl];
  const float* arow = seq + ((size_t)b * S_ + sidx) * D_ + g * 8;

  // B rows: cls_w is [A][3][D] == [n][D] with n = a*3+c
  const int nb = nh * 48 + r16;
  const float* b0p = cw + (size_t)(nb +  0) * D_ + g * 8;
  const float* b1p = cw + (size_t)(nb + 16) * D_ + g * 8;
  const float* b2p = cw + (size_t)(nb + 32) * D_ + g * 8;

  f32x4 acc0 = {0.f,0.f,0.f,0.f};
  f32x4 acc1 = {0.f,0.f,0.f,0.f};
  f32x4 acc2 = {0.f,0.f,0.f,0.f};

  for (int kk = 0; kk < D_; kk += 32) {
    f32x4 alo  = *(const f32x4*)(arow + kk);
    f32x4 ahi  = *(const f32x4*)(arow + kk + 4);
    f32x4 b0lo = *(const f32x4*)(b0p + kk);
    f32x4 b0hi = *(const f32x4*)(b0p + kk + 4);
    f32x4 b1lo = *(const f32x4*)(b1p + kk);
    f32x4 b1hi = *(const f32x4*)(b1p + kk + 4);
    f32x4 b2lo = *(const f32x4*)(b2p + kk);
    f32x4 b2hi = *(const f32x4*)(b2p + kk + 4);
    bfrag af = cvt8(alo, ahi);
    acc0 = __builtin_amdgcn_mfma_f32_16x16x32_bf16(af, cvt8(b0lo, b0hi), acc0, 0, 0, 0);
    acc1 = __builtin_amdgcn_mfma_f32_16x16x32_bf16(af, cvt8(b1lo, b1hi), acc1, 0, 0, 0);
    acc2 = __builtin_amdgcn_mfma_f32_16x16x32_bf16(af, cvt8(b2lo, b2hi), acc2, 0, 0, 0);
  }

  // C/D layout (HW-verified): reg j of lane l holds D[(l>>4)*4 + j][l&15]
  {
    const int wl0 = msub * 16 + g * 4;
    const float bias0 = cb[nh * 48 +      r16];
    const float bias1 = cb[nh * 48 + 16 + r16];
    const float bias2 = cb[nh * 48 + 32 + r16];
    #pragma unroll
    for (int j = 0; j < 4; ++j) {
      lds[wl0 + j][nh * 48 +      r16] = acc0[j] + bias0;
      lds[wl0 + j][nh * 48 + 16 + r16] = acc1[j] + bias1;
      lds[wl0 + j][nh * 48 + 32 + r16] = acc2[j] + bias2;
    }
  }
  __syncthreads();

  // Coalesced output: per attribute a, 32 w x 3 c = 96 contiguous floats at
  // out[((a*B + b)*W + w0)*3]. 768 float4s total, 3 per thread.
  #pragma unroll
  for (int it = 0; it < 3; ++it) {
    const int f4i = tid + it * 256;     // 0..767
    const int a   = f4i / 24;           // 24 float4s per attribute
    const int e0  = (f4i % 24) * 4;     // element offset within the 96-float stream
    float vv[4];
    #pragma unroll
    for (int u = 0; u < 4; ++u) {
      const int e = e0 + u;
      vv[u] = lds[e / 3][a * 3 + e % 3];
    }
    float* op = out + ((size_t)(a * B_ + b) * W_ + w0) * 3 + e0;
    *(float4*)op = make_float4(vv[0], vv[1], vv[2], vv[3]);
  }
}

extern "C" void kernel_launch(void* const* d_in, const int* in_sizes, int n_in,
                              void* d_out, int out_size, void* d_ws, size_t ws_size,
                              hipStream_t stream) {
  const float* seq  = (const float*)d_in[0];   // [64, 512, 768] fp32
  const int*   widx = (const int*)d_in[1];     // [64, 256] int32
  const float* cw   = (const float*)d_in[2];   // [32, 3, 768] fp32
  const float* cb   = (const float*)d_in[3];   // [32, 3] fp32
  float* out = (float*)d_out;                  // [32, 64, 256, 3] fp32

  dim3 grid(B_ * (W_ / 32));   // 512 blocks
  dim3 block(256);
  ner_mfma_kernel<<<grid, block, 0, stream>>>(seq, widx, cw, cb, out);
}

// Round 2
// 143.489 us; speedup vs baseline: 1.1709x; 1.1709x over previous
//
#include <hip/hip_runtime.h>
#include <hip/hip_bf16.h>

// Problem constants
#define B_    64
#define S_    512
#define W_    256
#define D_    768
#define NN    96    // 32 attrs * 3 classes
#define BK    64    // K-chunk in floats
#define NCH   12    // 768 / 64

typedef __attribute__((ext_vector_type(8))) short bfrag;   // 8 bf16 (16 B)
typedef __attribute__((ext_vector_type(4))) float f32x4;
typedef __attribute__((ext_vector_type(4))) short s16x4;   // 4 bf16 (8 B)

static __device__ __forceinline__ short f2bf(float f) {
  __hip_bfloat16 h = __float2bfloat16(f);
  return __builtin_bit_cast(short, h);
}
static __device__ __forceinline__ s16x4 pack4(f32x4 v) {
  s16x4 r;
  r[0] = f2bf(v[0]); r[1] = f2bf(v[1]); r[2] = f2bf(v[2]); r[3] = f2bf(v[3]);
  return r;
}

// Block: one b, 32 w-rows x all 96 cols. 768 threads = 12 waves.
// Wave wv: m-tile (wv&1), n-tile (wv>>1) -> one 16x16 MFMA accumulator.
// K-loop: 12 chunks of BK=64, LDS-staged bf16 with XOR-swizzled 128B rows,
// register prefetch of chunk c+1 overlapping compute of chunk c.
__global__ __launch_bounds__(768, 6) void ner_kernel(
    const float* __restrict__ seq, const int* __restrict__ widx,
    const float* __restrict__ cw, const float* __restrict__ cb,
    float* __restrict__ out)
{
  __shared__ union {
    struct {
      short a[32 * 64];   // gathered A chunk, bf16, row = w-row (128 B/row, swizzled)
      short b[96 * 64];   // B chunk, bf16, row = n (128 B/row, swizzled)
    } s;
    float o[32 * 100];    // output staging (row-pad 100 floats vs 96)
  } u;

  const int tid = threadIdx.x;
  const int blk = blockIdx.x;
  const int b   = blk >> 3;            // 8 blocks per batch element
  const int w0  = (blk & 7) << 5;      // 32 w-rows per block

  // ---- staging roles (coalesced: 16 consecutive lanes = 256 B of one row) ----
  const int srow = tid >> 4;           // 0..47
  const int kc   = tid & 15;           // float4 index within 64-float chunk
  const float* aptr = nullptr;
  if (tid < 512) {                     // waves 0-7 stage A (rows 0..31)
    const int sidx = widx[b * W_ + w0 + srow];
    aptr = seq + ((size_t)b * S_ + sidx) * D_ + kc * 4;
  }
  const int brow1 = srow + 48;         // rows 48..95
  const float* bptr0 = cw + (size_t)srow  * D_ + kc * 4;
  const float* bptr1 = cw + (size_t)brow1 * D_ + kc * 4;

  // ---- compute roles ----
  const int lane = tid & 63;
  const int wv   = tid >> 6;           // 0..11
  const int mt   = wv & 1;
  const int nt   = wv >> 1;            // 0..5
  const int r16  = lane & 15;
  const int g    = lane >> 4;

  const int am = mt * 16 + r16;        // A LDS row for this lane's fragment
  const int bn = nt * 16 + r16;        // B LDS row

  f32x4 acc = {0.f, 0.f, 0.f, 0.f};

  char* const la = (char*)u.s.a;
  char* const lb = (char*)u.s.b;

  // prefetch chunk 0
  f32x4 ra, rb0, rb1;
  if (tid < 512) ra = *(const f32x4*)(aptr);
  rb0 = *(const f32x4*)(bptr0);
  rb1 = *(const f32x4*)(bptr1);

  for (int c = 0; c < NCH; ++c) {
    __syncthreads();   // previous chunk's ds_reads complete -> LDS reusable
    if (tid < 512)
      *(s16x4*)(la + srow  * 128 + ((kc * 8) ^ ((srow  & 7) << 4))) = pack4(ra);
    *(s16x4*)(lb + srow  * 128 + ((kc * 8) ^ ((srow  & 7) << 4))) = pack4(rb0);
    *(s16x4*)(lb + brow1 * 128 + ((kc * 8) ^ ((brow1 & 7) << 4))) = pack4(rb1);
    __syncthreads();   // LDS chunk ready
    if (c + 1 < NCH) { // issue next chunk's loads; latency hides under MFMA phase
      const int k0 = (c + 1) * BK;
      if (tid < 512) ra = *(const f32x4*)(aptr + k0);
      rb0 = *(const f32x4*)(bptr0 + k0);
      rb1 = *(const f32x4*)(bptr1 + k0);
    }
    #pragma unroll
    for (int ks = 0; ks < 2; ++ks) {
      bfrag af = *(const bfrag*)(la + am * 128 + (((ks * 64) + g * 16) ^ ((am & 7) << 4)));
      bfrag bf = *(const bfrag*)(lb + bn * 128 + (((ks * 64) + g * 16) ^ ((bn & 7) << 4)));
      acc = __builtin_amdgcn_mfma_f32_16x16x32_bf16(af, bf, acc, 0, 0, 0);
    }
  }

  __syncthreads();     // all compute done; reuse LDS as fp32 out-staging
  {
    // C/D layout: reg j of lane l -> D[(l>>4)*4 + j][l&15]
    const int n    = nt * 16 + r16;
    const float bias = cb[n];
    const int row0 = mt * 16 + g * 4;
    #pragma unroll
    for (int j = 0; j < 4; ++j)
      u.o[(row0 + j) * 100 + n] = acc[j] + bias;
  }
  __syncthreads();
  {
    // Coalesced stores: per attribute a, 32 rows x 3 = 96 contiguous floats.
    // 768 float4 total = exactly 1 per thread.
    const int a  = tid / 24;           // 0..31
    const int e0 = (tid % 24) * 4;     // 0..92
    float vv[4];
    #pragma unroll
    for (int q = 0; q < 4; ++q) {
      const int e = e0 + q;
      vv[q] = u.o[(e / 3) * 100 + a * 3 + (e - (e / 3) * 3)];
    }
    float* op = out + ((size_t)(a * B_ + b) * W_ + w0) * 3 + e0;
    *(float4*)op = make_float4(vv[0], vv[1], vv[2], vv[3]);
  }
}

extern "C" void kernel_launch(void* const* d_in, const int* in_sizes, int n_in,
                              void* d_out, int out_size, void* d_ws, size_t ws_size,
                              hipStream_t stream) {
  const float* seq  = (const float*)d_in[0];   // [64, 512, 768] fp32
  const int*   widx = (const int*)d_in[1];     // [64, 256] int32
  const float* cw   = (const float*)d_in[2];   // [32, 3, 768] fp32
  const float* cb   = (const float*)d_in[3];   // [32, 3] fp32
  float* out = (float*)d_out;                  // [32, 64, 256, 3] fp32

  dim3 grid(B_ * (W_ / 32));   // 512 blocks
  dim3 block(768);             // 12 waves
  ner_kernel<<<grid, block, 0, stream>>>(seq, widx, cw, cb, out);
}